// Round 1
// baseline (240.789 us; speedup 1.0000x reference)
//
#include <hip/hip_runtime.h>

// Multi-head VQ: inputs (16,2048,1024) f32, embeddings (4,64,256) f32.
// Outputs flat f32: quantized_st[33554432] | loss[1] | indices[131072 as float].

#define HH   4
#define KK   64
#define HD   256
#define DD   1024
#define NTOK 32768
#define NDQ  33554432ull
#define TPB  128      // tokens per block
#define EPAD 257      // 257 % 32 == 1 -> bank (k+d)%32 across 64 lanes = 2-way (free)

__global__ __launch_bounds__(256, 2) void vq_main(
    const float* __restrict__ x, const float* __restrict__ emb,
    float* __restrict__ out, double* __restrict__ partial)
{
    __shared__ float e_lds[KK * EPAD];
    __shared__ float cb_sq_lds[KK];
    __shared__ float loss_lds[4];

    const int h = blockIdx.y;
    const float* eh = emb + (size_t)h * KK * HD;   // 16384 floats

    // Stage codebook for this head into LDS (padded rows), float4 loads.
    for (int i = threadIdx.x; i < KK * HD / 4; i += 256) {
        float4 v = ((const float4*)eh)[i];
        int base = i * 4;
        int k = base >> 8, dd = base & 255;
        float* p = &e_lds[k * EPAD + dd];
        p[0] = v.x; p[1] = v.y; p[2] = v.z; p[3] = v.w;
    }
    __syncthreads();

    // codebook_sq[k] = sum_d e^2 (products rounded, then summed — like ref)
    if (threadIdx.x < KK) {
        const int k = threadIdx.x;
        float s = 0.f;
        for (int d = 0; d < HD; ++d) {
            float e = e_lds[k * EPAD + d];
            float p = e * e;
            s += p;
        }
        cb_sq_lds[k] = s;
    }
    __syncthreads();

    const int lane = threadIdx.x & 63;
    const int wave = __builtin_amdgcn_readfirstlane(threadIdx.x >> 6);
    const float cbq = cb_sq_lds[lane];
    float loss_acc = 0.f;

    for (int g = wave; g < TPB / 8; g += 4) {
        const int tok0 = blockIdx.x * TPB + g * 8;
        const float* xbase = x + (size_t)tok0 * DD + (size_t)h * HD;

        float acc[8] = {0.f,0.f,0.f,0.f,0.f,0.f,0.f,0.f};
        for (int d0 = 0; d0 < HD; d0 += 8) {
            float ev[8];
            #pragma unroll
            for (int j = 0; j < 8; ++j) ev[j] = e_lds[lane * EPAD + d0 + j];
            #pragma unroll
            for (int t = 0; t < 8; ++t) {
                const float* xp = xbase + (size_t)t * DD + d0;   // wave-uniform -> s_load
                #pragma unroll
                for (int j = 0; j < 8; ++j)
                    acc[t] = __builtin_fmaf(xp[j], ev[j], acc[t]);
            }
        }

        for (int t = 0; t < 8; ++t) {
            const int n = tok0 + t;
            const float* xp = xbase + (size_t)t * DD;
            float4 x4 = *(const float4*)(xp + lane * 4);

            // input_sq: rounded products, tree sum (close to ref's reduction)
            float p0 = x4.x * x4.x, p1 = x4.y * x4.y;
            float p2 = x4.z * x4.z, p3 = x4.w * x4.w;
            float isq = (p0 + p1) + (p2 + p3);
            #pragma unroll
            for (int m = 1; m < 64; m <<= 1) isq += __shfl_xor(isq, m);

            // dist rounding order matches ref: (isq + cbq) - 2*dot
            float dist = (isq + cbq) - 2.0f * acc[t];

            // argmin with first-index tie-break (lexicographic butterfly)
            float bv = dist; int bi = lane;
            #pragma unroll
            for (int m = 1; m < 64; m <<= 1) {
                float ov = __shfl_xor(bv, m);
                int   oi = __shfl_xor(bi, m);
                if (ov < bv || (ov == bv && oi < bi)) { bv = ov; bi = oi; }
            }
            const int kst = __builtin_amdgcn_readfirstlane(bi);

            // q from global codebook (L2-resident 256KB)
            float4 q4 = *(const float4*)(eh + (size_t)kst * HD + lane * 4);

            // quantized_st = x + (q - x), faithful to ref rounding
            float d0v = q4.x - x4.x, d1v = q4.y - x4.y;
            float d2v = q4.z - x4.z, d3v = q4.w - x4.w;
            float4 st;
            st.x = x4.x + d0v; st.y = x4.y + d1v;
            st.z = x4.z + d2v; st.w = x4.w + d3v;
            *(float4*)(out + (size_t)n * DD + (size_t)h * HD + lane * 4) = st;

            loss_acc = __builtin_fmaf(d0v, d0v, loss_acc);
            loss_acc = __builtin_fmaf(d1v, d1v, loss_acc);
            loss_acc = __builtin_fmaf(d2v, d2v, loss_acc);
            loss_acc = __builtin_fmaf(d3v, d3v, loss_acc);

            if (lane == 0)
                out[NDQ + 1 + (size_t)n * HH + h] = (float)kst;
        }
    }

    // block loss partial (deterministic: fixed tree, fixed block->slot map)
    #pragma unroll
    for (int m = 1; m < 64; m <<= 1) loss_acc += __shfl_xor(loss_acc, m);
    if (lane == 0) loss_lds[wave] = loss_acc;
    __syncthreads();
    if (threadIdx.x == 0) {
        double s = ((double)loss_lds[0] + (double)loss_lds[1])
                 + ((double)loss_lds[2] + (double)loss_lds[3]);
        partial[(size_t)blockIdx.y * gridDim.x + blockIdx.x] = s;
    }
}

__global__ void vq_finalize(const double* __restrict__ partial,
                            float* __restrict__ out, int nparts)
{
    const int lane = threadIdx.x & 63;
    double s = 0.0;
    for (int i = lane; i < nparts; i += 64) s += partial[i];
    #pragma unroll
    for (int m = 1; m < 64; m <<= 1) s += __shfl_xor(s, m);
    if (lane == 0) {
        float mv = (float)(s / (double)NDQ);
        out[NDQ] = mv + 0.5f * mv;   // q_latent + 0.5*e_latent, both == mv
    }
}

extern "C" void kernel_launch(void* const* d_in, const int* in_sizes, int n_in,
                              void* d_out, int out_size, void* d_ws, size_t ws_size,
                              hipStream_t stream)
{
    const float* x   = (const float*)d_in[0];
    const float* emb = (const float*)d_in[1];
    float* out = (float*)d_out;
    double* partial = (double*)d_ws;   // 1024 doubles, all overwritten each launch

    dim3 grid(NTOK / TPB, HH);
    vq_main<<<grid, dim3(256), 0, stream>>>(x, emb, out, partial);
    vq_finalize<<<1, dim3(64), 0, stream>>>(partial, out, (NTOK / TPB) * HH);
}